// Round 13
// baseline (443.647 us; speedup 1.0000x reference)
//
#include <hip/hip_runtime.h>
#include <hip/hip_bf16.h>

#define N 20000
#define E 200000
#define IN 128
#define OUT 128
#define NB 8
#define SI 16
#define SO 16
#define R 230
#define T 365
#define MSG_CHUNKS 8

// All scratch in module .bss — d_ws untouched, no runtime API calls in
// kernel_launch (graph-capture-proven structure).
__device__ float g_msg[(size_t)E * OUT];   // messages, stored in DST-SORTED order
__device__ float g_agg[(size_t)N * OUT];
__device__ int   g_deg[N];                 // dst in-degree
__device__ int   g_off[N + 1];             // dst CSR offsets
__device__ int   g_cur[N];                 // dst scatter cursors
__device__ int   g_rdeg[R];                // edges per relation
__device__ int   g_roff[R + 1];            // rel CSR offsets
__device__ int   g_rcur[R];                // rel scatter cursors
__device__ int   g_rsrc[E];                // rel-sorted: source node
__device__ int   g_rpos[E];                // rel-sorted: dst-order slot
__device__ float g_rnrm[E];                // rel-sorted: edge norm

__global__ void zero_kernel() {
    int i = blockIdx.x * blockDim.x + threadIdx.x;
    if (i < N) g_deg[i] = 0;
    if (i < R) g_rdeg[i] = 0;
}

__global__ void count_kernel(const int* __restrict__ edge_dst,
                             const int* __restrict__ edge_type) {
    int e = blockIdx.x * blockDim.x + threadIdx.x;
    if (e >= E) return;
    atomicAdd(&g_deg[edge_dst[e]], 1);
    atomicAdd(&g_rdeg[edge_type[e]], 1);
}

// Exclusive prefix sums: dst (N=20000, parallel) + rel (R=230, serial on t0).
__global__ __launch_bounds__(1024) void scan_kernel() {
    __shared__ int part[1024];
    const int t = threadIdx.x;
    const int base = t * 20;
    int csum = 0;
    int d[20];
#pragma unroll
    for (int k = 0; k < 20; ++k) {
        int idx = base + k;
        d[k] = (idx < N) ? g_deg[idx] : 0;
        csum += d[k];
    }
    part[t] = csum;
    __syncthreads();
    for (int off = 1; off < 1024; off <<= 1) {
        int v = (t >= off) ? part[t - off] : 0;
        __syncthreads();
        part[t] += v;
        __syncthreads();
    }
    int run = part[t] - csum;
#pragma unroll
    for (int k = 0; k < 20; ++k) {
        int idx = base + k;
        if (idx < N) {
            g_off[idx] = run;
            g_cur[idx] = run;
            run += d[k];
        }
    }
    if (t == 1023) g_off[N] = part[1023];
    if (t == 0) {   // serial scan over 230 relation counts
        int acc = 0;
        for (int r = 0; r < R; ++r) {
            g_roff[r] = acc;
            g_rcur[r] = acc;
            acc += g_rdeg[r];
        }
        g_roff[R] = acc;
    }
}

// One pass: assign each edge its dst-order slot AND bucket it by relation.
__global__ void scatter_kernel(const int* __restrict__ edge_src,
                               const int* __restrict__ edge_dst,
                               const int* __restrict__ edge_type,
                               const float* __restrict__ edge_norm) {
    int e = blockIdx.x * blockDim.x + threadIdx.x;
    if (e >= E) return;
    int pd = atomicAdd(&g_cur[edge_dst[e]], 1);   // slot in dst order
    int pr = atomicAdd(&g_rcur[edge_type[e]], 1); // slot in rel order
    g_rsrc[pr] = edge_src[e];
    g_rpos[pr] = pd;
    g_rnrm[pr] = edge_norm[e];
}

// Relation-sorted message GEMM. Block = (relation, chunk), 256 threads =
// 2 edge-groups x 128 outputs. W_r column (16 floats) held in REGISTERS for
// the whole block -> weight traffic ~15 MB total (vs 1.65 GB in R12).
// h row staged in LDS (coalesced); message written contiguously to its
// dst-order slot so the agg kernel streams sequentially.
__global__ __launch_bounds__(256) void msg_kernel(const float* __restrict__ h,
                                                  const float* __restrict__ weight) {
    const int r = blockIdx.x / MSG_CHUNKS;
    const int c = blockIdx.x % MSG_CHUNKS;
    const int t = threadIdx.x;
    const int g = t >> 7;         // edge group 0/1
    const int o = t & 127;        // output feature
    const int b = o >> 4, ol = o & 15;

    const int j0 = g_roff[r], j1 = g_roff[r + 1];
    const int len = j1 - j0;
    const int s0 = j0 + (int)(((long)len * c) / MSG_CHUNKS);
    const int s1 = j0 + (int)(((long)len * (c + 1)) / MSG_CHUNKS);

    float w[SI];
#pragma unroll
    for (int i = 0; i < SI; ++i)
        w[i] = weight[(long)r * (NB * SI * SO) + b * (SI * SO) + i * SO + ol];

    __shared__ float hs[2][IN];
    for (int base = s0; base < s1; base += 2) {
        int j = base + g;
        bool valid = (j < s1);
        int s = 0, pd = 0;
        float nr = 0.f;
        if (valid) {
            s  = g_rsrc[j];
            pd = g_rpos[j];
            nr = g_rnrm[j];
            hs[g][o] = h[(long)s * IN + o];   // coalesced 512B per group
        }
        __syncthreads();
        if (valid) {
            const float4* hp = reinterpret_cast<const float4*>(&hs[g][b * SI]);
            float dot = 0.f;
#pragma unroll
            for (int q = 0; q < 4; ++q) {
                float4 hv = hp[q];
                dot = fmaf(hv.x, w[4 * q + 0], dot);
                dot = fmaf(hv.y, w[4 * q + 1], dot);
                dot = fmaf(hv.z, w[4 * q + 2], dot);
                dot = fmaf(hv.w, w[4 * q + 3], dot);
            }
            g_msg[(long)pd * OUT + o] = dot * nr;  // contiguous 512B burst
        }
        __syncthreads();
    }
}

// Streaming aggregation: node n's messages are rows off[n]..off[n+1] of g_msg
// — fully sequential float4 reads. 128 thr = 4 edge-lanes x 32 quads.
__global__ __launch_bounds__(128) void agg_kernel() {
    const int n   = blockIdx.x;
    const int tid = threadIdx.x;
    const int el  = tid >> 5;
    const int q   = tid & 31;
    const int j0 = g_off[n], j1 = g_off[n + 1];
    float4 acc = make_float4(0.f, 0.f, 0.f, 0.f);
    for (int j = j0 + el; j < j1; j += 4) {
        float4 v = reinterpret_cast<const float4*>(g_msg)[(long)j * 32 + q];
        acc.x += v.x; acc.y += v.y; acc.z += v.z; acc.w += v.w;
    }
    __shared__ float4 red[128];
    red[tid] = acc;
    __syncthreads();
    if (tid < 64) {
        float4 a = red[tid], c = red[tid + 64];
        a.x += c.x; a.y += c.y; a.z += c.z; a.w += c.w;
        red[tid] = a;
    }
    __syncthreads();
    if (tid < 32) {
        float4 a = red[tid], c = red[tid + 32];
        a.x += c.x; a.y += c.y; a.z += c.z; a.w += c.w;
        reinterpret_cast<float4*>(g_agg)[(long)n * 32 + tid] = a;
    }
}

// 16 nodes per block, 128 threads (thread = out feature). Unchanged.
__global__ __launch_bounds__(128) void node_kernel(
        const float* __restrict__ h,
        const float* __restrict__ node_norm,
        const float* __restrict__ h_bias,
        const float* __restrict__ loop_weight,
        const float* __restrict__ time_embed,
        const int* __restrict__ time_idx,
        float* __restrict__ out) {
    __shared__ float hsm[IN * 16];
    const int tid  = threadIdx.x;
    const int base = blockIdx.x * 16;

    for (int k = tid; k < 16 * IN; k += 128) {
        int nl = k >> 7;
        int i  = k & 127;
        hsm[i * 16 + nl] = h[(long)(base + nl) * IN + i];
    }
    __syncthreads();

    float acc[16];
#pragma unroll
    for (int nl = 0; nl < 16; ++nl) acc[nl] = 0.f;

    for (int i = 0; i < IN; ++i) {
        float w = loop_weight[(long)i * OUT + tid];
        const float4* hp = reinterpret_cast<const float4*>(&hsm[i * 16]);
#pragma unroll
        for (int q = 0; q < 4; ++q) {
            float4 hv = hp[q];
            acc[q * 4 + 0] = fmaf(hv.x, w, acc[q * 4 + 0]);
            acc[q * 4 + 1] = fmaf(hv.y, w, acc[q * 4 + 1]);
            acc[q * 4 + 2] = fmaf(hv.z, w, acc[q * 4 + 2]);
            acc[q * 4 + 3] = fmaf(hv.w, w, acc[q * 4 + 3]);
        }
    }

    float bias = h_bias[tid];
#pragma unroll
    for (int nl = 0; nl < 16; ++nl) {
        int n = base + nl;
        float v = g_agg[(long)n * OUT + tid] * node_norm[n] + bias + acc[nl];
        out[(long)n * OUT + tid] = fmaxf(v, 0.f);
        out[(long)N * OUT + (long)n * IN + tid] =
            time_embed[(long)time_idx[n] * IN + tid];
    }
}

extern "C" void kernel_launch(void* const* d_in, const int* in_sizes, int n_in,
                              void* d_out, int out_size, void* d_ws, size_t ws_size,
                              hipStream_t stream) {
    const float* h           = (const float*)d_in[0];
    const float* edge_norm   = (const float*)d_in[1];
    const float* node_norm   = (const float*)d_in[2];
    const float* weight      = (const float*)d_in[3];
    const float* h_bias      = (const float*)d_in[4];
    const float* loop_weight = (const float*)d_in[5];
    const float* time_embed  = (const float*)d_in[6];
    const int*   edge_src    = (const int*)d_in[7];
    const int*   edge_dst    = (const int*)d_in[8];
    const int*   edge_type   = (const int*)d_in[9];
    const int*   time_idx    = (const int*)d_in[10];
    float* out = (float*)d_out;

    zero_kernel<<<(N + 255) / 256, 256, 0, stream>>>();
    count_kernel<<<(E + 255) / 256, 256, 0, stream>>>(edge_dst, edge_type);
    scan_kernel<<<1, 1024, 0, stream>>>();
    scatter_kernel<<<(E + 255) / 256, 256, 0, stream>>>(
        edge_src, edge_dst, edge_type, edge_norm);

    msg_kernel<<<R * MSG_CHUNKS, 256, 0, stream>>>(h, weight);
    agg_kernel<<<N, 128, 0, stream>>>();

    node_kernel<<<N / 16, 128, 0, stream>>>(
        h, node_norm, h_bias, loop_weight, time_embed, time_idx, out);
}

// Round 14
// 304.922 us; speedup vs baseline: 1.4550x; 1.4550x over previous
//
#include <hip/hip_runtime.h>
#include <hip/hip_bf16.h>

#define N 20000
#define E 200000
#define IN 128
#define OUT 128
#define NB 8
#define SI 16
#define SO 16
#define R 230
#define T 365
#define NCHUNK 782            // ceil(E/256)
#define MSG_CHUNKS 8

// All scratch in module .bss — d_ws untouched, no runtime API calls in
// kernel_launch (graph-capture-proven structure).
__device__ float g_msg[(size_t)E * OUT];   // messages in DST-SORTED order (102 MB)
__device__ int   g_deg[N];
__device__ int   g_off[N + 1];             // dst CSR offsets
__device__ int   g_cur[N];                 // dst scatter cursors (low contention)
__device__ int   g_hist[NCHUNK * R];       // per-chunk rel histogram -> bases (in place)
__device__ int   g_rdeg[R];
__device__ int   g_roff[R + 1];
__device__ int   g_rsrc[E];                // rel-sorted: source node
__device__ int   g_rpos[E];                // rel-sorted: dst-order slot
__device__ float g_rnrm[E];                // rel-sorted: edge norm

__global__ void zero_kernel() {
    int i = blockIdx.x * blockDim.x + threadIdx.x;
    if (i < N) g_deg[i] = 0;
}

// Per-chunk rel histogram in LDS (privatized — no 230-address global atomics)
// plus dst degree counting (20000 addresses, low contention).
__global__ __launch_bounds__(256) void count_kernel(const int* __restrict__ edge_dst,
                                                    const int* __restrict__ edge_type) {
    __shared__ int cnt[R];
    const int t = threadIdx.x;
    if (t < R) cnt[t] = 0;
    __syncthreads();
    int e = blockIdx.x * 256 + t;
    if (e < E) {
        atomicAdd(&cnt[edge_type[e]], 1);       // LDS atomic
        atomicAdd(&g_deg[edge_dst[e]], 1);      // global, ~10 edges/addr
    }
    __syncthreads();
    if (t < R) g_hist[blockIdx.x * R + t] = cnt[t];
}

// Part A: dst exclusive scan (N=20000). Part B: per-rel running sum over the
// 782 chunk histograms (230 threads, batched loads) -> in-place chunk bases;
// then serial 230-rel roff scan on t0.
__global__ __launch_bounds__(1024) void scan_kernel() {
    __shared__ int part[1024];
    const int t = threadIdx.x;
    const int base = t * 20;
    int csum = 0;
    int d[20];
#pragma unroll
    for (int k = 0; k < 20; ++k) {
        int idx = base + k;
        d[k] = (idx < N) ? g_deg[idx] : 0;
        csum += d[k];
    }
    part[t] = csum;
    __syncthreads();
    for (int off = 1; off < 1024; off <<= 1) {
        int v = (t >= off) ? part[t - off] : 0;
        __syncthreads();
        part[t] += v;
        __syncthreads();
    }
    int run = part[t] - csum;
#pragma unroll
    for (int k = 0; k < 20; ++k) {
        int idx = base + k;
        if (idx < N) {
            g_off[idx] = run;
            g_cur[idx] = run;
            run += d[k];
        }
    }
    if (t == 1023) g_off[N] = part[1023];

    // Part B: rel chunk-bases. Batch loads of 8 to keep them independent.
    if (t < R) {
        int acc = 0;
        int c = 0;
        for (; c + 8 <= NCHUNK; c += 8) {
            int v0 = g_hist[(c + 0) * R + t];
            int v1 = g_hist[(c + 1) * R + t];
            int v2 = g_hist[(c + 2) * R + t];
            int v3 = g_hist[(c + 3) * R + t];
            int v4 = g_hist[(c + 4) * R + t];
            int v5 = g_hist[(c + 5) * R + t];
            int v6 = g_hist[(c + 6) * R + t];
            int v7 = g_hist[(c + 7) * R + t];
            g_hist[(c + 0) * R + t] = acc; acc += v0;
            g_hist[(c + 1) * R + t] = acc; acc += v1;
            g_hist[(c + 2) * R + t] = acc; acc += v2;
            g_hist[(c + 3) * R + t] = acc; acc += v3;
            g_hist[(c + 4) * R + t] = acc; acc += v4;
            g_hist[(c + 5) * R + t] = acc; acc += v5;
            g_hist[(c + 6) * R + t] = acc; acc += v6;
            g_hist[(c + 7) * R + t] = acc; acc += v7;
        }
        for (; c < NCHUNK; ++c) {
            int v = g_hist[c * R + t];
            g_hist[c * R + t] = acc; acc += v;
        }
        g_rdeg[t] = acc;
    }
    __syncthreads();
    if (t == 0) {
        int acc = 0;
        for (int r = 0; r < R; ++r) {
            g_roff[r] = acc;
            acc += g_rdeg[r];
        }
        g_roff[R] = acc;
    }
}

// Counting-sort scatter: local rank via LDS atomic, global slot = roff +
// chunk base + rank. Only low-contention global atomics (dst cursors).
__global__ __launch_bounds__(256) void scatter_kernel(const int* __restrict__ edge_src,
                                                      const int* __restrict__ edge_dst,
                                                      const int* __restrict__ edge_type,
                                                      const float* __restrict__ edge_norm) {
    __shared__ int cnt[R];
    const int t = threadIdx.x;
    if (t < R) cnt[t] = 0;
    __syncthreads();
    int e = blockIdx.x * 256 + t;
    if (e < E) {
        int r = edge_type[e];
        int d = edge_dst[e];
        int lr = atomicAdd(&cnt[r], 1);                 // LDS atomic
        int pd = atomicAdd(&g_cur[d], 1);               // global, low contention
        int pr = g_roff[r] + g_hist[blockIdx.x * R + r] + lr;
        g_rsrc[pr] = edge_src[e];
        g_rpos[pr] = pd;
        g_rnrm[pr] = edge_norm[e];
    }
}

// Rel-sorted message GEMM. Block = (relation, chunk); 256 thr = 2 independent
// 128-thread groups (no LDS, no barriers). W_r column lives in registers for
// the whole block; h read as lane-broadcast float4 (L2-resident);
// message written contiguously to its dst-order slot.
__global__ __launch_bounds__(256) void msg_kernel(const float* __restrict__ h,
                                                  const float* __restrict__ weight) {
    const int r = blockIdx.x >> 3;
    const int c = blockIdx.x & 7;
    const int t = threadIdx.x;
    const int g = t >> 7;          // group 0/1
    const int o = t & 127;         // output feature
    const int b = o >> 4, ol = o & 15;

    const int j0 = g_roff[r], j1 = g_roff[r + 1];

    float w[SI];
#pragma unroll
    for (int i = 0; i < SI; ++i)
        w[i] = weight[(long)r * (NB * SI * SO) + b * (SI * SO) + i * SO + ol];

    const int unit = c * 2 + g;    // 0..15
    for (int j = j0 + unit; j < j1; j += 16) {
        int   s  = g_rsrc[j];      // wave-uniform
        int   pd = g_rpos[j];
        float nr = g_rnrm[j];
        const float4* hp = reinterpret_cast<const float4*>(h + (long)s * IN + b * SI);
        float dot = 0.f;
#pragma unroll
        for (int q = 0; q < 4; ++q) {
            float4 hv = hp[q];
            dot = fmaf(hv.x, w[4 * q + 0], dot);
            dot = fmaf(hv.y, w[4 * q + 1], dot);
            dot = fmaf(hv.z, w[4 * q + 2], dot);
            dot = fmaf(hv.w, w[4 * q + 3], dot);
        }
        g_msg[(long)pd * OUT + o] = dot * nr;   // contiguous 512B per group
    }
}

// Fused: loop GEMM + streaming msg aggregation (node n's messages are a
// contiguous span of g_msg) + epilogue + time-embedding gather.
__global__ __launch_bounds__(128) void node_kernel(
        const float* __restrict__ h,
        const float* __restrict__ node_norm,
        const float* __restrict__ h_bias,
        const float* __restrict__ loop_weight,
        const float* __restrict__ time_embed,
        const int* __restrict__ time_idx,
        float* __restrict__ out) {
    __shared__ float hsm[IN * 16];
    const int tid  = threadIdx.x;
    const int base = blockIdx.x * 16;

    for (int k = tid; k < 16 * IN; k += 128) {
        int nl = k >> 7;
        int i  = k & 127;
        hsm[i * 16 + nl] = h[(long)(base + nl) * IN + i];
    }
    __syncthreads();

    float acc[16];
#pragma unroll
    for (int nl = 0; nl < 16; ++nl) acc[nl] = 0.f;

    for (int i = 0; i < IN; ++i) {
        float w = loop_weight[(long)i * OUT + tid];
        const float4* hp = reinterpret_cast<const float4*>(&hsm[i * 16]);
#pragma unroll
        for (int q = 0; q < 4; ++q) {
            float4 hv = hp[q];
            acc[q * 4 + 0] = fmaf(hv.x, w, acc[q * 4 + 0]);
            acc[q * 4 + 1] = fmaf(hv.y, w, acc[q * 4 + 1]);
            acc[q * 4 + 2] = fmaf(hv.z, w, acc[q * 4 + 2]);
            acc[q * 4 + 3] = fmaf(hv.w, w, acc[q * 4 + 3]);
        }
    }

    float bias = h_bias[tid];
#pragma unroll
    for (int nl = 0; nl < 16; ++nl) {
        int n = base + nl;
        int j0 = g_off[n], j1 = g_off[n + 1];
        float agg = 0.f;
        int j = j0;
        for (; j + 2 <= j1; j += 2) {
            float v0 = g_msg[(long)j * OUT + tid];
            float v1 = g_msg[(long)(j + 1) * OUT + tid];
            agg += v0 + v1;
        }
        if (j < j1) agg += g_msg[(long)j * OUT + tid];
        float v = agg * node_norm[n] + bias + acc[nl];
        out[(long)n * OUT + tid] = fmaxf(v, 0.f);
        out[(long)N * OUT + (long)n * IN + tid] =
            time_embed[(long)time_idx[n] * IN + tid];
    }
}

extern "C" void kernel_launch(void* const* d_in, const int* in_sizes, int n_in,
                              void* d_out, int out_size, void* d_ws, size_t ws_size,
                              hipStream_t stream) {
    const float* h           = (const float*)d_in[0];
    const float* edge_norm   = (const float*)d_in[1];
    const float* node_norm   = (const float*)d_in[2];
    const float* weight      = (const float*)d_in[3];
    const float* h_bias      = (const float*)d_in[4];
    const float* loop_weight = (const float*)d_in[5];
    const float* time_embed  = (const float*)d_in[6];
    const int*   edge_src    = (const int*)d_in[7];
    const int*   edge_dst    = (const int*)d_in[8];
    const int*   edge_type   = (const int*)d_in[9];
    const int*   time_idx    = (const int*)d_in[10];
    float* out = (float*)d_out;

    zero_kernel<<<(N + 255) / 256, 256, 0, stream>>>();
    count_kernel<<<NCHUNK, 256, 0, stream>>>(edge_dst, edge_type);
    scan_kernel<<<1, 1024, 0, stream>>>();
    scatter_kernel<<<NCHUNK, 256, 0, stream>>>(
        edge_src, edge_dst, edge_type, edge_norm);

    msg_kernel<<<R * MSG_CHUNKS, 256, 0, stream>>>(h, weight);

    node_kernel<<<N / 16, 128, 0, stream>>>(
        h, node_norm, h_bias, loop_weight, time_embed, time_idx, out);
}